// Round 1
// baseline (81.059 us; speedup 1.0000x reference)
//
#include <hip/hip_runtime.h>

// ContinuousCRF: mean-field CRF on a 96x96 grid, 3 classes, 5 iterations.
// Key insight: the dense [N,N] pairwise kernel is a translation-invariant
// 11x11 circular-mask convolution (radius 5, weight exp(-dist), no center tap).
// Each iteration: q = softmax(unary + Comp @ conv(q)).
// We store logits z between iterations and recompute the cheap 3-class
// softmax for the halo region inside each kernel.

constexpr int HH = 96, WW = 96, NN = HH * WW;
constexpr int TILE = 16, HALO = 5, EXT = TILE + 2 * HALO; // 26

template <bool FIRST, bool LAST>
__global__ __launch_bounds__(TILE * TILE) void crf_iter(
    const float* __restrict__ unary,   // [3][9216] planes
    const float* __restrict__ comp,    // [3][3]
    const float4* __restrict__ zin,    // [9216] logits (x,y,z used), ignored if FIRST
    float4* __restrict__ zout,         // [9216] logits out (if !LAST)
    float* __restrict__ qout)          // [3][9216] final q (if LAST)
{
    __shared__ float4 qs[EXT][EXT];    // softmax'd q over tile+halo
    __shared__ float wtab[121];        // 11x11 conv weights

    const int tx = threadIdx.x, ty = threadIdx.y;
    const int tid = ty * TILE + tx;

    // Build the convolution weight table (once per block; exact math).
    if (tid < 121) {
        int dy = tid / 11 - 5, dx = tid % 11 - 5;
        int d2 = dy * dy + dx * dx;
        wtab[tid] = (d2 > 0 && d2 <= 25) ? expf(-sqrtf((float)d2)) : 0.0f;
    }

    const int bx0 = blockIdx.x * TILE, by0 = blockIdx.y * TILE;

    // Stage softmax(z) for the 26x26 halo tile into LDS. Out-of-image -> q=0
    // (matches zero connectivity outside the grid).
    for (int i = tid; i < EXT * EXT; i += TILE * TILE) {
        int hy = i / EXT, hx = i - hy * EXT;
        int gy = by0 + hy - HALO, gx = bx0 + hx - HALO;
        float4 q = make_float4(0.f, 0.f, 0.f, 0.f);
        if (gy >= 0 && gy < HH && gx >= 0 && gx < WW) {
            int n = gy * WW + gx;
            float z0, z1, z2;
            if (FIRST) {
                z0 = unary[n];
                z1 = unary[NN + n];
                z2 = unary[2 * NN + n];
            } else {
                float4 z = zin[n];
                z0 = z.x; z1 = z.y; z2 = z.z;
            }
            float mx = fmaxf(z0, fmaxf(z1, z2));
            float e0 = expf(z0 - mx), e1 = expf(z1 - mx), e2 = expf(z2 - mx);
            float inv = 1.0f / (e0 + e1 + e2);
            q = make_float4(e0 * inv, e1 * inv, e2 * inv, 0.f);
        }
        qs[hy][hx] = q;
    }
    __syncthreads();

    // 11x11 convolution, static per-row dx bounds (circle mask) -> 81 taps.
    float m0 = 0.f, m1 = 0.f, m2 = 0.f;
    constexpr int XLO[11] = {5, 2, 1, 1, 1, 0, 1, 1, 1, 2, 5};
    constexpr int XHI[11] = {5, 8, 9, 9, 9, 10, 9, 9, 9, 8, 5};
#pragma unroll
    for (int dyi = 0; dyi < 11; ++dyi) {
#pragma unroll
        for (int dxi = XLO[dyi]; dxi <= XHI[dyi]; ++dxi) {
            float w = wtab[dyi * 11 + dxi];   // wave-uniform broadcast read
            float4 q = qs[ty + dyi][tx + dxi];
            m0 = fmaf(w, q.x, m0);
            m1 = fmaf(w, q.y, m1);
            m2 = fmaf(w, q.z, m2);
        }
    }

    // comp_msg[c] = sum_d comp[c][d] * messages[d]  (comp is 3x3 row-major)
    float t0 = comp[0] * m0 + comp[1] * m1 + comp[2] * m2;
    float t1 = comp[3] * m0 + comp[4] * m1 + comp[5] * m2;
    float t2 = comp[6] * m0 + comp[7] * m1 + comp[8] * m2;

    const int n = (by0 + ty) * WW + (bx0 + tx);
    float z0 = unary[n] + t0;
    float z1 = unary[NN + n] + t1;
    float z2 = unary[2 * NN + n] + t2;

    if (LAST) {
        float mx = fmaxf(z0, fmaxf(z1, z2));
        float e0 = expf(z0 - mx), e1 = expf(z1 - mx), e2 = expf(z2 - mx);
        float inv = 1.0f / (e0 + e1 + e2);
        qout[n] = e0 * inv;
        qout[NN + n] = e1 * inv;
        qout[2 * NN + n] = e2 * inv;
    } else {
        zout[n] = make_float4(z0, z1, z2, 0.f);
    }
}

extern "C" void kernel_launch(void* const* d_in, const int* in_sizes, int n_in,
                              void* d_out, int out_size, void* d_ws, size_t ws_size,
                              hipStream_t stream) {
    const float* unary = (const float*)d_in[0];
    const float* comp = (const float*)d_in[1];
    float* out = (float*)d_out;

    // Ping-pong logit buffers in workspace: 2 * 9216 * 16 B = 288 KiB.
    float4* zA = (float4*)d_ws;
    float4* zB = zA + NN;

    dim3 grid(WW / TILE, HH / TILE);  // 6x6
    dim3 block(TILE, TILE);           // 256 threads

    crf_iter<true,  false><<<grid, block, 0, stream>>>(unary, comp, nullptr, zA, nullptr);
    crf_iter<false, false><<<grid, block, 0, stream>>>(unary, comp, zA, zB, nullptr);
    crf_iter<false, false><<<grid, block, 0, stream>>>(unary, comp, zB, zA, nullptr);
    crf_iter<false, false><<<grid, block, 0, stream>>>(unary, comp, zA, zB, nullptr);
    crf_iter<false, true ><<<grid, block, 0, stream>>>(unary, comp, zB, nullptr, out);
}